// Round 4
// baseline (1352.024 us; speedup 1.0000x reference)
//
#include <hip/hip_runtime.h>
#include <cstdint>
#include <cstddef>

// ---------------------------------------------------------------------------
// VelocityHead fused kernel, fp32.
//
// Algebra (per point n, b = batch_idx[n]):
//   s[o]  = sum_c M[o,c]*x0[c] + bb[b,o],   M = gw@lw0, bb = M@t_bias[b]+gw@lb+gb
//   g     = sigmoid(s)
//   v[c]  = sum_o lw1[o,c] * g[o] * fw1[o]
//   out[l]= sum_c x1[l,c] * gate[b,c] * v[c]        (l = 0..2)
// The silu/out0 branch of the reference is dead (out[:,0,:] discarded).
//
// ws layout (floats), B = 512:
//   [0,16384)            W1g  : [c][o] = M[o][c]   (transposed M)
//   [16384,16512)        bprime[o] = gw@lb + gb
//   [16512,16512+B*128)  gate[b][c] = 1 + t_scale
//   [+B*128)             bb[b][o]
//
// k_main: 512 threads (8 waves -> 2 waves/SIMD for latency hiding).
//   tx = tid&31 owns outputs o/c = 4tx..4tx+3 (slot tx%8 spans all 8 LDS
//   bank quads); ty = tid>>5 (0..15) owns points p = 4ty..4ty+3 (TPT=64).
// WX (gated mv1 output) stored [p][o] with float4-slot swizzle j ^ (p&7):
//   mv2 reads are conflict-free 2-address broadcasts.
// LDS: W1 64KB + W2 64KB + XB 32KB = 160KB exactly -> 1 block/CU.
// ---------------------------------------------------------------------------

#define TPT 64  // points per tile in k_main

// ---- kernel A: M^T and bprime --------------------------------------------
__global__ __launch_bounds__(256) void k_prep(const float* __restrict__ lw,
                                              const float* __restrict__ lb,
                                              const float* __restrict__ gw,
                                              const float* __restrict__ gb,
                                              float* __restrict__ ws) {
  int gid = blockIdx.x;
  if (gid < 64) {
    int g = gid * 256 + threadIdx.x;        // 0..16383
    int c = g & 127, o = g >> 7;
    const float* lw0 = lw;                  // lw[0]
    float acc = 0.f;
    #pragma unroll 4
    for (int j = 0; j < 128; ++j) acc += gw[o * 128 + j] * lw0[j * 128 + c];
    ws[c * 128 + o] = acc;                  // W1g[c][o] = M[o][c]
  } else {
    int o = threadIdx.x;
    if (o < 128) {
      float acc = gb[o];
      for (int j = 0; j < 128; ++j) acc += gw[o * 128 + j] * lb[j];
      ws[16384 + o] = acc;                  // bprime
    }
  }
}

// ---- kernel B: time MLP + per-batch tables --------------------------------
__global__ __launch_bounds__(128) void k_time(const float* __restrict__ t,
                                              const float* __restrict__ w1,
                                              const float* __restrict__ b1,
                                              const float* __restrict__ w2,
                                              const float* __restrict__ b2,
                                              float* __restrict__ ws, int B) {
  __shared__ float temb[64];
  __shared__ float hm[128];
  __shared__ float tb[128];
  int b = blockIdx.x;
  int h = threadIdx.x;
  float tv = t[b];
  if (h < 32) {
    // freqs = exp(-ln(10000) * i / 32)
    float fr = expf(-9.210340371976184f * (float)h / 32.f);
    float arg = tv * fr;
    temb[h] = sinf(arg);
    temb[32 + h] = cosf(arg);
  }
  __syncthreads();
  // hmid = silu(temb @ w1^T + b1)
  float pre = b1[h];
  #pragma unroll 4
  for (int d = 0; d < 64; ++d) pre += temb[d] * w1[h * 64 + d];
  hm[h] = pre / (1.f + expf(-pre));
  __syncthreads();
  // t_params = hm @ w2^T + b2 ; bias = [:128], gate = 1 + [128:]
  float p0 = b2[h], p1 = b2[128 + h];
  #pragma unroll 4
  for (int d = 0; d < 128; ++d) {
    float hv = hm[d];
    p0 += hv * w2[h * 128 + d];
    p1 += hv * w2[(128 + h) * 128 + d];
  }
  tb[h] = p0;
  float* gate_g = ws + 16512;
  float* bb_g   = gate_g + (size_t)B * 128;
  gate_g[b * 128 + h] = 1.f + p1;
  __syncthreads();
  // bb[b][o] = bprime[o] + sum_c W1g[c][o] * t_bias[b][c]
  float acc = ws[16384 + h];
  #pragma unroll 4
  for (int c = 0; c < 128; ++c) acc += ws[c * 128 + h] * tb[c];
  bb_g[b * 128 + h] = acc;
}

// ---- kernel C: the fused per-point kernel ---------------------------------
__global__ __launch_bounds__(512, 2) void k_main(const float* __restrict__ x,
                                                 const int* __restrict__ bidx,
                                                 const float* __restrict__ lw,
                                                 const float* __restrict__ fw,
                                                 const float* __restrict__ ws,
                                                 float* __restrict__ out,
                                                 int N, int NTiles, int B) {
  __shared__ __align__(16) float W1[128 * 128];  // [k][o] = M[o][k]
  __shared__ __align__(16) float W2[128 * 128];  // [o][c] = lw1 rows (as stored)
  __shared__ __align__(16) float XB[64 * 128];   // x0 tile [p][c]; reused as WX [p][o] swizzled

  const int tid = threadIdx.x;
  const int tx = tid & 31;        // output slice o/c = 4tx..4tx+3
  const int ty = tid >> 5;        // 0..15, points p = 4ty..4ty+3

  // stage weights once per block (L2-resident, 128KB)
  {
    const float4* s1 = (const float4*)ws;               // W1g
    const float4* s2 = (const float4*)(lw + 16384);     // lw1
    float4* d1 = (float4*)W1;
    float4* d2 = (float4*)W2;
    #pragma unroll
    for (int i = 0; i < 8; ++i) {
      d1[tid + i * 512] = s1[tid + i * 512];
      d2[tid + i * 512] = s2[tid + i * 512];
    }
  }
  const float* gate_g = ws + 16512;
  const float* bb_g   = gate_g + (size_t)B * 128;

  // fw1 slice for this thread (constant across tiles): c = 4tx..4tx+3
  float4 f1r = *(const float4*)(fw + 128 + 4 * tx);

  float4 st[4];  // staged x0 for next tile
  const int grid = (int)gridDim.x;

  // ---- stage helpers (x0 tile, linear [p][c] layout, coalesced float4) ----
  auto issue_stage = [&](int tt) {
    int n0 = tt * TPT;
    #pragma unroll
    for (int i = 0; i < 4; ++i) {
      int idx = tid + i * 512;
      int p = idx >> 5, c4 = idx & 31;
      int n = n0 + p; if (n >= N) n = N - 1;
      st[i] = *(const float4*)(x + (size_t)n * 1152 + c4 * 4);
    }
  };
  auto write_stage = [&]() {
    float4* xb4 = (float4*)XB;
    #pragma unroll
    for (int i = 0; i < 4; ++i) xb4[tid + i * 512] = st[i];
  };

  int t0 = blockIdx.x;
  if (t0 < NTiles) { issue_stage(t0); write_stage(); }

  for (int t = t0; t < NTiles; t += grid) {
    __syncthreads();  // XB(t) visible
    const int n0 = t * TPT;

    // ---- batch idx + bias init: acc[oj][pj] = bb[b[p]][4tx+oj] ----
    int bi[4];
    float acc[4][4];
    #pragma unroll
    for (int pj = 0; pj < 4; ++pj) {
      int n = n0 + 4 * ty + pj; if (n >= N) n = N - 1;
      bi[pj] = bidx[n];
      float4 br = *(const float4*)(bb_g + (size_t)bi[pj] * 128 + 4 * tx);
      acc[0][pj] = br.x; acc[1][pj] = br.y; acc[2][pj] = br.z; acc[3][pj] = br.w;
    }

    // ---- mv1: s += M @ x0  (W1[k][o] slots, XB[p][k]) ----
    {
      const float4* w1p = (const float4*)W1;
      const float* xb0 = XB + (4 * ty) * 128;
      #pragma unroll 4
      for (int k4 = 0; k4 < 32; ++k4) {
        float ar[4][4];
        #pragma unroll
        for (int pj = 0; pj < 4; ++pj)
          *(float4*)&ar[pj][0] = *(const float4*)(xb0 + pj * 128 + k4 * 4);
        #pragma unroll
        for (int u = 0; u < 4; ++u) {
          float4 w = w1p[(k4 * 4 + u) * 32 + tx];   // o = 4tx..4tx+3
          #pragma unroll
          for (int pj = 0; pj < 4; ++pj) {
            float xv = ar[pj][u];
            acc[0][pj] += w.x * xv; acc[1][pj] += w.y * xv;
            acc[2][pj] += w.z * xv; acc[3][pj] += w.w * xv;
          }
        }
      }
    }

    // ---- sigmoid * fw1 -> wv ----
    float wv[4][4];
    #pragma unroll
    for (int oj = 0; oj < 4; ++oj) {
      float fo = (oj == 0) ? f1r.x : (oj == 1) ? f1r.y : (oj == 2) ? f1r.z : f1r.w;
      #pragma unroll
      for (int pj = 0; pj < 4; ++pj) {
        float g = 1.f / (1.f + __expf(-acc[oj][pj]));
        wv[oj][pj] = g * fo;
      }
    }

    __syncthreads();  // all mv1 reads of XB done
    // ---- write WX[p][o]: float4 slot tx stored at tx ^ (p&7) ----
    #pragma unroll
    for (int pj = 0; pj < 4; ++pj) {
      int p = 4 * ty + pj;
      float4 q = make_float4(wv[0][pj], wv[1][pj], wv[2][pj], wv[3][pj]);
      ((float4*)XB)[p * 32 + (tx ^ (p & 7))] = q;
    }
    __syncthreads();

    // ---- mv2: v[c] = sum_o lw1[o][c] * w[p][o] ----
    float ac2[4][4];
    #pragma unroll
    for (int cj = 0; cj < 4; ++cj)
      #pragma unroll
      for (int pj = 0; pj < 4; ++pj) ac2[cj][pj] = 0.f;
    {
      const float4* w2p = (const float4*)W2;
      const float4* wx4 = (const float4*)XB;
      #pragma unroll 4
      for (int o4 = 0; o4 < 32; ++o4) {
        float a2r[4][4];
        #pragma unroll
        for (int pj = 0; pj < 4; ++pj) {
          int p = 4 * ty + pj;
          *(float4*)&a2r[pj][0] = *(const float4*)&wx4[p * 32 + (o4 ^ (p & 7))];
        }
        #pragma unroll
        for (int u = 0; u < 4; ++u) {
          float4 w = w2p[(o4 * 4 + u) * 32 + tx];   // c = 4tx..4tx+3
          #pragma unroll
          for (int pj = 0; pj < 4; ++pj) {
            float wvv = a2r[pj][u];
            ac2[0][pj] += w.x * wvv; ac2[1][pj] += w.y * wvv;
            ac2[2][pj] += w.z * wvv; ac2[3][pj] += w.w * wvv;
          }
        }
      }
    }
    __syncthreads();  // WX reads done; XB free for next tile's stage

    // prefetch next tile's x0 while we do phase C
    bool more = (t + grid) < NTiles;
    if (more) issue_stage(t + grid);

    // ---- fold gate: V = v * gate[b[p]] ----
    #pragma unroll
    for (int pj = 0; pj < 4; ++pj) {
      float4 gr = *(const float4*)(gate_g + (size_t)bi[pj] * 128 + 4 * tx);
      ac2[0][pj] *= gr.x; ac2[1][pj] *= gr.y; ac2[2][pj] *= gr.z; ac2[3][pj] *= gr.w;
    }

    // ---- phase C: out[p][l] = sum_c x1[p][l][c] * V[p][c] ----
    float part[4][3];
    #pragma unroll
    for (int pj = 0; pj < 4; ++pj) {
      int n = n0 + 4 * ty + pj;
      int nc = n >= N ? N - 1 : n;
      #pragma unroll
      for (int l = 0; l < 3; ++l) {
        float4 xr = *(const float4*)(x + (size_t)nc * 1152 + (1 + l) * 128 + 4 * tx);
        part[pj][l] = xr.x * ac2[0][pj] + xr.y * ac2[1][pj] +
                      xr.z * ac2[2][pj] + xr.w * ac2[3][pj];
      }
    }
    // reduce across the 32 tx lanes (butterfly)
    #pragma unroll
    for (int m = 1; m < 32; m <<= 1)
      #pragma unroll
      for (int pj = 0; pj < 4; ++pj)
        #pragma unroll
        for (int l = 0; l < 3; ++l)
          part[pj][l] += __shfl_xor(part[pj][l], m, 64);

    if (tx == 0) {
      if (n0 + TPT <= N) {
        // 12 contiguous floats, 16B-aligned (n0+4ty multiple of 4)
        float4* ob = (float4*)(out + (size_t)(n0 + 4 * ty) * 3);
        ob[0] = make_float4(part[0][0], part[0][1], part[0][2], part[1][0]);
        ob[1] = make_float4(part[1][1], part[1][2], part[2][0], part[2][1]);
        ob[2] = make_float4(part[2][2], part[3][0], part[3][1], part[3][2]);
      } else {
        #pragma unroll
        for (int pj = 0; pj < 4; ++pj) {
          int n = n0 + 4 * ty + pj;
          if (n < N) {
            out[(size_t)n * 3 + 0] = part[pj][0];
            out[(size_t)n * 3 + 1] = part[pj][1];
            out[(size_t)n * 3 + 2] = part[pj][2];
          }
        }
      }
    }

    if (more) write_stage();  // safe: barrier after mv2 already passed
  }
}

// ---------------------------------------------------------------------------
extern "C" void kernel_launch(void* const* d_in, const int* in_sizes, int n_in,
                              void* d_out, int out_size, void* d_ws, size_t ws_size,
                              hipStream_t stream) {
  const float* x      = (const float*)d_in[0];
  const float* t      = (const float*)d_in[1];
  const int*   bidx   = (const int*)d_in[2];
  const float* tm_w1  = (const float*)d_in[3];
  const float* tm_b1  = (const float*)d_in[4];
  const float* tm_w2  = (const float*)d_in[5];
  const float* tm_b2  = (const float*)d_in[6];
  const float* lw     = (const float*)d_in[7];
  const float* lb     = (const float*)d_in[8];
  const float* gw     = (const float*)d_in[9];
  const float* gb     = (const float*)d_in[10];
  const float* fw     = (const float*)d_in[11];
  // d_in[12] = fb (zero, unused: out row 0 is discarded)

  float* out = (float*)d_out;
  float* ws  = (float*)d_ws;

  int N = in_sizes[0] / (9 * 128);
  int B = in_sizes[1];
  int NTiles = (N + TPT - 1) / TPT;

  hipLaunchKernelGGL(k_prep, dim3(65), dim3(256), 0, stream, lw, lb, gw, gb, ws);
  hipLaunchKernelGGL(k_time, dim3(B), dim3(128), 0, stream,
                     t, tm_w1, tm_b1, tm_w2, tm_b2, ws, B);
  int grid = NTiles < 256 ? NTiles : 256;
  hipLaunchKernelGGL(k_main, dim3(grid), dim3(512), 0, stream,
                     x, bidx, lw, fw, ws, out, N, NTiles, B);
}

// Round 5
// 1244.496 us; speedup vs baseline: 1.0864x; 1.0864x over previous
//
#include <hip/hip_runtime.h>
#include <cstdint>
#include <cstddef>

// ---------------------------------------------------------------------------
// VelocityHead fused kernel, fp32.
//
// Algebra (per point n, b = batch_idx[n]):
//   s[o]  = sum_c M[o,c]*x0[c] + bb[b,o],   M = gw@lw0, bb = M@t_bias[b]+gw@lb+gb
//   g     = sigmoid(s)
//   v[c]  = sum_o lw1[o,c] * g[o] * fw1[o]
//   out[l]= sum_c x1[l,c] * gate[b,c] * v[c]        (l = 0..2)
// The silu/out0 branch of the reference is dead (out[:,0,:] discarded).
//
// ws layout (floats), B = 512:
//   [0,16384)            W1g  : [k][o] = M[o][k]   (transposed M)
//   [16384,16512)        bprime[o] = gw@lb + gb
//   [16512,16512+B*128)  gate[b][c] = 1 + t_scale
//   [+B*128)             bb[b][o]
//
// k_main mapping (512 thr = 8 waves, 2 blocks/CU):
//   lane (tid&63) = point p of the 64-point tile; wave (tid>>6) owns the
//   16-wide output slice ob=16*wave. Weights are wave-UNIFORM -> scalar
//   s_load stream (SMEM pipe, not LDS). Per-lane activation rows live in
//   LDS with an XOR float4-slot swizzle (slot j holds data j^(p&7)):
//   staged via global_load_lds with PRE-SWIZZLED GLOBAL source (linear LDS
//   dest), read back per-lane -> 8 lanes per bank-quad = conflict-free.
//   LDS: XB 32KB + WX 32KB + PS 6KB = 70KB -> 2 blocks/CU (4 waves/SIMD).
// ---------------------------------------------------------------------------

#define TPT 64  // points per tile in k_main

// ---- kernel A: M^T and bprime --------------------------------------------
__global__ __launch_bounds__(256) void k_prep(const float* __restrict__ lw,
                                              const float* __restrict__ lb,
                                              const float* __restrict__ gw,
                                              const float* __restrict__ gb,
                                              float* __restrict__ ws) {
  int gid = blockIdx.x;
  if (gid < 64) {
    int g = gid * 256 + threadIdx.x;        // 0..16383
    int c = g & 127, o = g >> 7;
    const float* lw0 = lw;                  // lw[0]
    float acc = 0.f;
    #pragma unroll 4
    for (int j = 0; j < 128; ++j) acc += gw[o * 128 + j] * lw0[j * 128 + c];
    ws[c * 128 + o] = acc;                  // W1g[k=c][o] = M[o][c]
  } else {
    int o = threadIdx.x;
    if (o < 128) {
      float acc = gb[o];
      for (int j = 0; j < 128; ++j) acc += gw[o * 128 + j] * lb[j];
      ws[16384 + o] = acc;                  // bprime
    }
  }
}

// ---- kernel B: time MLP + per-batch tables --------------------------------
__global__ __launch_bounds__(128) void k_time(const float* __restrict__ t,
                                              const float* __restrict__ w1,
                                              const float* __restrict__ b1,
                                              const float* __restrict__ w2,
                                              const float* __restrict__ b2,
                                              float* __restrict__ ws, int B) {
  __shared__ float temb[64];
  __shared__ float hm[128];
  __shared__ float tb[128];
  int b = blockIdx.x;
  int h = threadIdx.x;
  float tv = t[b];
  if (h < 32) {
    float fr = expf(-9.210340371976184f * (float)h / 32.f);
    float arg = tv * fr;
    temb[h] = sinf(arg);
    temb[32 + h] = cosf(arg);
  }
  __syncthreads();
  float pre = b1[h];
  #pragma unroll 4
  for (int d = 0; d < 64; ++d) pre += temb[d] * w1[h * 64 + d];
  hm[h] = pre / (1.f + expf(-pre));
  __syncthreads();
  float p0 = b2[h], p1 = b2[128 + h];
  #pragma unroll 4
  for (int d = 0; d < 128; ++d) {
    float hv = hm[d];
    p0 += hv * w2[h * 128 + d];
    p1 += hv * w2[(128 + h) * 128 + d];
  }
  tb[h] = p0;
  float* gate_g = ws + 16512;
  float* bb_g   = gate_g + (size_t)B * 128;
  gate_g[b * 128 + h] = 1.f + p1;
  __syncthreads();
  float acc = ws[16384 + h];
  #pragma unroll 4
  for (int c = 0; c < 128; ++c) acc += ws[c * 128 + h] * tb[c];
  bb_g[b * 128 + h] = acc;
}

// ---- async global->LDS helper (width 16B, lane-linear dest) ---------------
__device__ __forceinline__ void gload_lds16(const void* g, void* l) {
  __builtin_amdgcn_global_load_lds(
      (const __attribute__((address_space(1))) void*)g,
      (__attribute__((address_space(3))) void*)l, 16, 0, 0);
}

// ---- kernel C: the fused per-point kernel ---------------------------------
__global__ __launch_bounds__(512, 4) void k_main(const float* __restrict__ x,
                                                 const int* __restrict__ bidx,
                                                 const float* __restrict__ lw,
                                                 const float* __restrict__ fw,
                                                 const float* __restrict__ ws,
                                                 float* __restrict__ out,
                                                 int N, int NTiles, int B) {
  __shared__ __align__(16) float XB[TPT * 128];   // x0 tile, swizzled slots
  __shared__ __align__(16) float WX[TPT * 128];   // wx tile,  swizzled slots
  __shared__ float PS[8 * TPT * 3];               // per-wave phase-C partials

  const int tid = threadIdx.x;
  const int wv_ = tid >> 6;                        // wave 0..7
  const int p   = tid & 63;                        // point in tile
  const int ps  = p & 7;                           // swizzle key
  const int ob  = __builtin_amdgcn_readfirstlane(wv_ * 16);  // output base

  const float* __restrict__ w1w = ws + ob;             // W1g[k][ob..], stride 128
  const float* __restrict__ w2w = lw + 16384 + ob;     // lw1[o][ob..], stride 128
  const float* gate_g = ws + 16512;
  const float* bb_g   = gate_g + (size_t)B * 128;

  // fw1 slice (wave-uniform constants)
  float f1[16];
  #pragma unroll
  for (int i = 0; i < 4; ++i)
    *(float4*)&f1[4 * i] = *(const float4*)(fw + 128 + ob + 4 * i);

  // ---- stage x0 tile: linear LDS dest, pre-swizzled global source ----
  auto stage = [&](int tt) {
    int n0 = tt * TPT;
    #pragma unroll
    for (int i = 0; i < 4; ++i) {
      int S  = (wv_ * 4 + i) * 64 + p;        // float4-slot this lane fills
      int sp = S >> 5, sj = S & 31;           // row, slot-in-row
      int n = n0 + sp; if (n >= N) n = N - 1;
      const float* src = x + (size_t)n * 1152 + ((sj ^ (sp & 7)) << 2);
      gload_lds16(src, XB + (size_t)(wv_ * 4 + i) * 256);  // uniform base
    }
  };

  // contiguous tile range per block (L2 + sorted-bidx locality)
  int nb   = (int)gridDim.x;
  int bpc  = NTiles / nb, rem = NTiles % nb;
  int bsel = (int)blockIdx.x;
  int tstart = bsel * bpc + (bsel < rem ? bsel : rem);
  int tcnt   = bpc + (bsel < rem ? 1 : 0);
  int tend   = tstart + tcnt;
  if (tcnt <= 0) return;

  stage(tstart);

  for (int t = tstart; t < tend; ++t) {
    const int n0 = t * TPT;
    asm volatile("s_waitcnt vmcnt(0)" ::: "memory");
    __syncthreads();                                   // (a) XB(t) ready

    int n = n0 + p; if (n >= N) n = N - 1;
    const int bi = bidx[n];

    // ---- mv1: acc[j] = bb[bi][ob+j] + sum_k W1g[k][ob+j] * x0[p][k] ----
    float acc[16];
    #pragma unroll
    for (int i = 0; i < 4; ++i) {
      float4 b4 = *(const float4*)(bb_g + (size_t)bi * 128 + ob + 4 * i);
      acc[4 * i + 0] = b4.x; acc[4 * i + 1] = b4.y;
      acc[4 * i + 2] = b4.z; acc[4 * i + 3] = b4.w;
    }
    #pragma unroll 4
    for (int k4 = 0; k4 < 32; ++k4) {
      float4 xv = *(const float4*)(XB + p * 128 + ((k4 ^ ps) << 2));
      const float* wr = w1w + (size_t)(k4 * 4) * 128;   // wave-uniform
      #pragma unroll
      for (int j = 0; j < 16; ++j) acc[j] = fmaf(wr[j], xv.x, acc[j]);
      #pragma unroll
      for (int j = 0; j < 16; ++j) acc[j] = fmaf(wr[128 + j], xv.y, acc[j]);
      #pragma unroll
      for (int j = 0; j < 16; ++j) acc[j] = fmaf(wr[256 + j], xv.z, acc[j]);
      #pragma unroll
      for (int j = 0; j < 16; ++j) acc[j] = fmaf(wr[384 + j], xv.w, acc[j]);
    }

    // ---- wv = sigmoid(acc) * fw1 -> WX (swizzled slots) ----
    #pragma unroll
    for (int i = 0; i < 4; ++i) {
      float4 q;
      q.x = f1[4 * i + 0] / (1.f + __expf(-acc[4 * i + 0]));
      q.y = f1[4 * i + 1] / (1.f + __expf(-acc[4 * i + 1]));
      q.z = f1[4 * i + 2] / (1.f + __expf(-acc[4 * i + 2]));
      q.w = f1[4 * i + 3] / (1.f + __expf(-acc[4 * i + 3]));
      *(float4*)(WX + p * 128 + (((wv_ * 4 + i) ^ ps) << 2)) = q;
    }
    __syncthreads();                                   // (c) WX ready, XB free

    if (t + 1 < tend) stage(t + 1);                    // overlaps mv2 + phase C

    // ---- mv2: ac2[j] = sum_o lw1[o][ob+j] * wx[p][o] ----
    float ac2[16];
    #pragma unroll
    for (int j = 0; j < 16; ++j) ac2[j] = 0.f;
    #pragma unroll 4
    for (int o4 = 0; o4 < 32; ++o4) {
      float4 wxv = *(const float4*)(WX + p * 128 + ((o4 ^ ps) << 2));
      const float* wr = w2w + (size_t)(o4 * 4) * 128;   // wave-uniform
      #pragma unroll
      for (int j = 0; j < 16; ++j) ac2[j] = fmaf(wr[j], wxv.x, ac2[j]);
      #pragma unroll
      for (int j = 0; j < 16; ++j) ac2[j] = fmaf(wr[128 + j], wxv.y, ac2[j]);
      #pragma unroll
      for (int j = 0; j < 16; ++j) ac2[j] = fmaf(wr[256 + j], wxv.z, ac2[j]);
      #pragma unroll
      for (int j = 0; j < 16; ++j) ac2[j] = fmaf(wr[384 + j], wxv.w, ac2[j]);
    }

    // ---- fold gate; phase C partials over this wave's 16 c's ----
    #pragma unroll
    for (int i = 0; i < 4; ++i) {
      float4 g4 = *(const float4*)(gate_g + (size_t)bi * 128 + ob + 4 * i);
      ac2[4 * i + 0] *= g4.x; ac2[4 * i + 1] *= g4.y;
      ac2[4 * i + 2] *= g4.z; ac2[4 * i + 3] *= g4.w;
    }
    float part[3];
    const float* xb1 = x + (size_t)n * 1152 + 128 + ob;
    #pragma unroll
    for (int l = 0; l < 3; ++l) {
      float s = 0.f;
      #pragma unroll
      for (int i = 0; i < 4; ++i) {
        float4 x4 = *(const float4*)(xb1 + l * 128 + 4 * i);
        s += x4.x * ac2[4 * i + 0] + x4.y * ac2[4 * i + 1] +
             x4.z * ac2[4 * i + 2] + x4.w * ac2[4 * i + 3];
      }
      part[l] = s;
    }
    PS[(wv_ * 64 + p) * 3 + 0] = part[0];
    PS[(wv_ * 64 + p) * 3 + 1] = part[1];
    PS[(wv_ * 64 + p) * 3 + 2] = part[2];
    __syncthreads();                                   // (d) partials ready

    // ---- cross-wave reduce + coalesced store (192 contiguous floats) ----
    if (tid < 192) {
      int q = tid / 3, l = tid - q * 3;
      float s = 0.f;
      #pragma unroll
      for (int w2 = 0; w2 < 8; ++w2) s += PS[(w2 * 64 + q) * 3 + l];
      if (n0 + q < N) out[(size_t)n0 * 3 + tid] = s;
    }
    // next PS write is 2+ barriers away ((a),(c) of t+1) -> race-free
  }
}

// ---------------------------------------------------------------------------
extern "C" void kernel_launch(void* const* d_in, const int* in_sizes, int n_in,
                              void* d_out, int out_size, void* d_ws, size_t ws_size,
                              hipStream_t stream) {
  const float* x      = (const float*)d_in[0];
  const float* t      = (const float*)d_in[1];
  const int*   bidx   = (const int*)d_in[2];
  const float* tm_w1  = (const float*)d_in[3];
  const float* tm_b1  = (const float*)d_in[4];
  const float* tm_w2  = (const float*)d_in[5];
  const float* tm_b2  = (const float*)d_in[6];
  const float* lw     = (const float*)d_in[7];
  const float* lb     = (const float*)d_in[8];
  const float* gw     = (const float*)d_in[9];
  const float* gb     = (const float*)d_in[10];
  const float* fw     = (const float*)d_in[11];
  // d_in[12] = fb (zero, unused: out row 0 is discarded)

  float* out = (float*)d_out;
  float* ws  = (float*)d_ws;

  int N = in_sizes[0] / (9 * 128);
  int B = in_sizes[1];
  int NTiles = (N + TPT - 1) / TPT;

  hipLaunchKernelGGL(k_prep, dim3(65), dim3(256), 0, stream, lw, lb, gw, gb, ws);
  hipLaunchKernelGGL(k_time, dim3(B), dim3(128), 0, stream,
                     t, tm_w1, tm_b1, tm_w2, tm_b2, ws, B);
  int grid = NTiles < 512 ? NTiles : 512;
  hipLaunchKernelGGL(k_main, dim3(grid), dim3(512), 0, stream,
                     x, bidx, lw, fw, ws, out, N, NTiles, B);
}